// Round 6
// baseline (256.612 us; speedup 1.0000x reference)
//
#include <hip/hip_runtime.h>

typedef __bf16 bf16x8 __attribute__((ext_vector_type(8)));
typedef float f32x4 __attribute__((ext_vector_type(4)));
typedef unsigned short u16;

__device__ __forceinline__ u16 f2bf(float f) {
    union { float f; unsigned u; } v; v.f = f;
    unsigned r = (v.u + 0x7FFFu + ((v.u >> 16) & 1u)) >> 16;
    return (u16)r;
}

__device__ __forceinline__ void fence_bar() {
    asm volatile("" ::: "memory");
    __builtin_amdgcn_s_barrier();
    asm volatile("" ::: "memory");
}

// ---- mask dtype detection + normalization ----------------------------------
__global__ __launch_bounds__(256)
void normMask(const unsigned int* __restrict__ m, unsigned char* __restrict__ nm) {
    __shared__ int isByte;
    if (threadIdx.x == 0) isByte = 0;
    __syncthreads();
    int bad = 0;
    for (int i = threadIdx.x; i < 2048; i += 256) bad |= (m[i] > 1u);
    if (bad) atomicOr(&isByte, 1);
    __syncthreads();
    if (isByte) {
        const unsigned char* mb = (const unsigned char*)m;
        for (int i = threadIdx.x; i < 8192; i += 256) nm[i] = mb[i] ? 1 : 0;
    } else {
        for (int i = threadIdx.x; i < 8192; i += 256) nm[i] = (unsigned char)m[i];
    }
}

// ---------------- W transpose+convert; 1/32 scale folded into Wq (exact) -----
__global__ __launch_bounds__(256)
void transW(const float* __restrict__ Wq, const float* __restrict__ Wk,
            const float* __restrict__ Wv, u16* __restrict__ Wt) {
    __shared__ u16 tile[64][65];
    const float* W = blockIdx.z == 0 ? Wq : (blockIdx.z == 1 ? Wk : Wv);
    const float sc = blockIdx.z == 0 ? 0.03125f : 1.0f;   // 2^-5: exponent-exact
    u16* out = Wt + (size_t)blockIdx.z * 1024 * 1024;
    int k0 = blockIdx.x * 64, n0 = blockIdx.y * 64;
    int t = threadIdx.x, cl = t & 63, rw = t >> 6;
    #pragma unroll
    for (int r = 0; r < 16; ++r) {
        int row = r * 4 + rw;
        tile[cl][row] = f2bf(W[(size_t)(k0 + row) * 1024 + n0 + cl] * sc);
    }
    __syncthreads();
    #pragma unroll
    for (int r = 0; r < 16; ++r) {
        int row = r * 4 + rw;
        out[(size_t)(n0 + row) * 1024 + k0 + cl] = tile[row][cl];
    }
}

// ---------------- x -> bf16 --------------------------------------------------
__global__ __launch_bounds__(256)
void convX(const float* __restrict__ x, u16* __restrict__ xb) {
    const size_t n4 = (size_t)8192 * 1024 / 4;
    for (size_t i = (size_t)blockIdx.x * 256 + threadIdx.x; i < n4; i += (size_t)gridDim.x * 256) {
        float4 v = ((const float4*)x)[i];
        ushort4 o = make_ushort4(f2bf(v.x), f2bf(v.y), f2bf(v.z), f2bf(v.w));
        ((ushort4*)xb)[i] = o;
    }
}

// ---------------- V transpose ------------------------------------------------
__global__ __launch_bounds__(256)
void transV(const u16* __restrict__ qkv, u16* __restrict__ vt) {
    __shared__ u16 tile[64][65];
    int b = blockIdx.z;
    int s0 = blockIdx.x * 64, d0 = blockIdx.y * 64;
    int t = threadIdx.x, cl = t & 63, rw = t >> 6;
    const u16* src = qkv + (size_t)b * 2048 * 3072 + 2048;
    #pragma unroll
    for (int r = 0; r < 16; ++r) {
        int row = r * 4 + rw;
        tile[cl][row] = src[(size_t)(s0 + row) * 3072 + d0 + cl];
    }
    __syncthreads();
    u16* dst = vt + (size_t)b * 1024 * 2048;
    #pragma unroll
    for (int r = 0; r < 16; ++r) {
        int row = r * 4 + rw;
        dst[(size_t)(d0 + row) * 2048 + s0 + cl] = tile[row][cl];
    }
}

// ============ 8-phase 256x256 GEMM + T2 swizzle (r4 schedule, 71.0us) =========
// OUTV==0: C bf16. OUTV==1: C fp32 + per-row (max,sumexp) partials per 64-col
// wave slice -> part[(z*32 + bcol/64 + wc)*2048 + row].
template <int OUTV>
__global__ __launch_bounds__(512, 2)
void gemm8p(const u16* __restrict__ A_, int lda, size_t sA,
            const u16* __restrict__ B_, int ldb, size_t sB,
            void* __restrict__ Cout, int ldc, size_t sC,
            int kdim, int ntiles, float2* __restrict__ partPtr) {
    __shared__ u16 lds[65536];   // A: [0,32768) ; B: [32768,65536)
    const u16* A = A_ + (size_t)blockIdx.z * sA;
    const u16* B = B_ + (size_t)blockIdx.z * sB;

    const int bid = blockIdx.x;
    const int brow = (bid / ntiles) * 256, bcol = (bid % ntiles) * 256;
    const int t = threadIdx.x;
    const int w = t >> 6, l = t & 63;
    const int wr = w >> 2, wc = w & 3;

    const int srow = t >> 3;                      // 0..63
    const int sslot = (t & 7) ^ (srow & 7);       // T2 pre-swizzled global slot
    const int aBase = (wr * 128 + (l & 15)) * 64;
    const int bBase = 32768 + (wc * 64 + (l & 15)) * 64;
    const int cx0 = (((l >> 4)) ^ (l & 7)) * 8;
    const int cx1 = (((l >> 4) + 4) ^ (l & 7)) * 8;

    auto lds3 = (__attribute__((address_space(3))) char*)lds;

    #define ISSUE(matB, q, tt, buf) do {                                           \
        const u16* gsrc = ((matB) ? B : A)                                         \
            + (size_t)(((matB) ? bcol : brow) + (q) * 64 + srow) * ((matB) ? ldb : lda) \
            + (size_t)(tt) * 64 + sslot * 8;                                       \
        const int dst_ = ((matB) ? 32768 : 0) + (buf) * 16384 + (q) * 4096 + t * 8; \
        __builtin_amdgcn_global_load_lds(                                          \
            (const __attribute__((address_space(1))) void*)gsrc,                   \
            (__attribute__((address_space(3))) void*)(lds3 + 2 * dst_), 16, 0, 0); \
    } while (0)

    f32x4 acc[8][4];
    #pragma unroll
    for (int m = 0; m < 8; ++m)
        #pragma unroll
        for (int n = 0; n < 4; ++n)
            acc[m][n] = (f32x4){0.f, 0.f, 0.f, 0.f};

    const int NT = kdim >> 6;

    // prologue: tile0 all 8 units; last two = A-q1,q3 (needed PH2 only)
    ISSUE(1, 0, 0, 0); ISSUE(1, 1, 0, 0); ISSUE(1, 2, 0, 0); ISSUE(1, 3, 0, 0);
    ISSUE(0, 0, 0, 0); ISSUE(0, 2, 0, 0); ISSUE(0, 1, 0, 0); ISSUE(0, 3, 0, 0);
    asm volatile("s_waitcnt vmcnt(2)" ::: "memory");
    fence_bar();

    for (int tt = 0; tt < NT; ++tt) {
        const int c = tt & 1;
        const int ab = c * 16384;
        const int nb = c ^ 1;
        const bool pf = (tt + 1 < NT);
        bf16x8 af[4], bfv[4];

        // ---- PH1: kk0, A m0-3 + B; issue B-q0,q1(t+1); vmcnt(2) ----
        #pragma unroll
        for (int m = 0; m < 4; ++m) af[m] = *(const bf16x8*)&lds[ab + aBase + m * 1024 + cx0];
        #pragma unroll
        for (int n = 0; n < 4; ++n) bfv[n] = *(const bf16x8*)&lds[ab + bBase + n * 1024 + cx0];
        if (pf) {
            ISSUE(1, 0, tt + 1, nb); ISSUE(1, 1, tt + 1, nb);
            asm volatile("s_waitcnt vmcnt(2)" ::: "memory");
        } else {
            asm volatile("s_waitcnt vmcnt(0)" ::: "memory");
        }
        fence_bar();
        __builtin_amdgcn_s_setprio(1);
        #pragma unroll
        for (int m = 0; m < 4; ++m)
            #pragma unroll
            for (int n = 0; n < 4; ++n)
                acc[m][n] = __builtin_amdgcn_mfma_f32_16x16x32_bf16(af[m], bfv[n], acc[m][n], 0, 0, 0);
        __builtin_amdgcn_s_setprio(0);
        fence_bar();

        // ---- PH2: kk0, A m4-7; issue B-q2,q3(t+1) ----
        #pragma unroll
        for (int m = 0; m < 4; ++m) af[m] = *(const bf16x8*)&lds[ab + aBase + (m + 4) * 1024 + cx0];
        if (pf) { ISSUE(1, 2, tt + 1, nb); ISSUE(1, 3, tt + 1, nb); }
        fence_bar();
        __builtin_amdgcn_s_setprio(1);
        #pragma unroll
        for (int m = 0; m < 4; ++m)
            #pragma unroll
            for (int n = 0; n < 4; ++n)
                acc[m + 4][n] = __builtin_amdgcn_mfma_f32_16x16x32_bf16(af[m], bfv[n], acc[m + 4][n], 0, 0, 0);
        __builtin_amdgcn_s_setprio(0);
        fence_bar();

        // ---- PH3: kk1, A m0-3 + B; issue A-q0,q2(t+1) ----
        #pragma unroll
        for (int m = 0; m < 4; ++m) af[m] = *(const bf16x8*)&lds[ab + aBase + m * 1024 + cx1];
        #pragma unroll
        for (int n = 0; n < 4; ++n) bfv[n] = *(const bf16x8*)&lds[ab + bBase + n * 1024 + cx1];
        if (pf) { ISSUE(0, 0, tt + 1, nb); ISSUE(0, 2, tt + 1, nb); }
        fence_bar();
        __builtin_amdgcn_s_setprio(1);
        #pragma unroll
        for (int m = 0; m < 4; ++m)
            #pragma unroll
            for (int n = 0; n < 4; ++n)
                acc[m][n] = __builtin_amdgcn_mfma_f32_16x16x32_bf16(af[m], bfv[n], acc[m][n], 0, 0, 0);
        __builtin_amdgcn_s_setprio(0);
        fence_bar();

        // ---- PH4: kk1, A m4-7; issue A-q1,q3(t+1); vmcnt(2) ----
        #pragma unroll
        for (int m = 0; m < 4; ++m) af[m] = *(const bf16x8*)&lds[ab + aBase + (m + 4) * 1024 + cx1];
        if (pf) {
            ISSUE(0, 1, tt + 1, nb); ISSUE(0, 3, tt + 1, nb);
            asm volatile("s_waitcnt vmcnt(2)" ::: "memory");
        } else {
            asm volatile("s_waitcnt vmcnt(0)" ::: "memory");
        }
        fence_bar();
        __builtin_amdgcn_s_setprio(1);
        #pragma unroll
        for (int m = 0; m < 4; ++m)
            #pragma unroll
            for (int n = 0; n < 4; ++n)
                acc[m + 4][n] = __builtin_amdgcn_mfma_f32_16x16x32_bf16(af[m], bfv[n], acc[m + 4][n], 0, 0, 0);
        __builtin_amdgcn_s_setprio(0);
        fence_bar();
    }
    #undef ISSUE

    // epilogue
    const int lr = (l >> 4) * 4, lc = l & 15;
    #pragma unroll
    for (int m = 0; m < 8; ++m) {
        #pragma unroll
        for (int n = 0; n < 4; ++n) {
            int rr = brow + wr * 128 + m * 16 + lr;
            int cc = bcol + wc * 64 + n * 16 + lc;
            #pragma unroll
            for (int j = 0; j < 4; ++j) {
                if constexpr (OUTV == 0)
                    ((u16*)Cout)[(size_t)blockIdx.z * sC + (size_t)(rr + j) * ldc + cc] = f2bf(acc[m][n][j]);
                else
                    ((float*)Cout)[(size_t)blockIdx.z * sC + (size_t)(rr + j) * ldc + cc] = acc[m][n][j];
            }
        }
    }
    if constexpr (OUTV == 1) {
        // per-row partials over this wave's 64 cols (4 n-frags x 16 lanes)
        float2* part = partPtr + ((size_t)blockIdx.z * 32 + (bcol >> 6) + wc) * 2048;
        #pragma unroll
        for (int m = 0; m < 8; ++m) {
            #pragma unroll
            for (int j = 0; j < 4; ++j) {
                float mx = fmaxf(fmaxf(acc[m][0][j], acc[m][1][j]),
                                 fmaxf(acc[m][2][j], acc[m][3][j]));
                #pragma unroll
                for (int o = 1; o < 16; o <<= 1) mx = fmaxf(mx, __shfl_xor(mx, o));
                float se = 0.f;
                #pragma unroll
                for (int n = 0; n < 4; ++n) se += __expf(acc[m][n][j] - mx);
                #pragma unroll
                for (int o = 1; o < 16; o <<= 1) se += __shfl_xor(se, o);
                if ((l & 15) == 0) {
                    int rr = brow + wr * 128 + m * 16 + (l >> 4) * 4 + j;
                    part[rr] = make_float2(mx, se);
                }
            }
        }
    }
}

// ---- combine per-row partials -> (max, invZ); masked rows -> (0, -1/2048) ---
__global__ __launch_bounds__(256)
void combineStats(const float2* __restrict__ part, float2* __restrict__ stats,
                  const unsigned char* __restrict__ nm, int bbase) {
    const int row = blockIdx.x * 256 + threadIdx.x;   // 0..2047
    const int z = blockIdx.y;
    if (nm[(bbase + z) * 2048 + row] == 0) {
        stats[z * 2048 + row] = make_float2(0.f, -(1.0f / 2048.0f));
        return;
    }
    const float2* p = part + (size_t)z * 32 * 2048 + row;
    float m = -1e30f;
    #pragma unroll
    for (int c = 0; c < 32; ++c) m = fmaxf(m, p[(size_t)c * 2048].x);
    float Z = 0.f;
    #pragma unroll
    for (int c = 0; c < 32; ++c) {
        float2 v = p[(size_t)c * 2048];
        Z += v.y * __expf(v.x - m);
    }
    stats[z * 2048 + row] = make_float2(m, 1.0f / Z);
}

// ---------------- PV GEMM with fused softmax on A-staging --------------------
// C[2048x1024] = P x vt^T, P formed on the fly: p = invZ<0 ? -invZ
//                                                 : exp(S - m) * invZ
__global__ __launch_bounds__(256, 2)
void gemm_pv(const float* __restrict__ S0, size_t sS,
             const float2* __restrict__ st0,
             const u16* __restrict__ B0, int ldb, size_t sB,
             float* __restrict__ Cout, int ldc, size_t sC, int kdim) {
    __shared__ u16 lA[128 * 64];
    __shared__ u16 lB[128 * 64];
    const float* S = S0 + (size_t)blockIdx.z * sS;
    const float2* st = st0 + (size_t)blockIdx.z * 2048;
    const u16* B = B0 + (size_t)blockIdx.z * sB;
    const int t = threadIdx.x;
    const int w = t >> 6, l = t & 63;
    const int wr = w >> 1, wc = w & 1;
    const int brow = blockIdx.x * 128, bcol = blockIdx.y * 128;
    const int rt = l >> 3;
    const int cb = (l & 7) * 8;

    auto ldsB3 = (__attribute__((address_space(3))) char*)lB;

    // per-chunk row stats (row fixed per p across the whole K loop)
    float sm[4], siz[4];
    #pragma unroll
    for (int p = 0; p < 4; ++p) {
        float2 v = st[brow + (p * 4 + w) * 8 + rt];
        sm[p] = v.x; siz[p] = v.y;
    }

    f32x4 acc[4][4];
    #pragma unroll
    for (int m = 0; m < 4; ++m)
        #pragma unroll
        for (int n = 0; n < 4; ++n)
            acc[m][n] = (f32x4){0.f, 0.f, 0.f, 0.f};

    for (int k0 = 0; k0 < kdim; k0 += 64) {
        __syncthreads();
        #pragma unroll
        for (int p = 0; p < 4; ++p) {
            int chunk = p * 4 + w;
            const u16* gb = B + (size_t)(bcol + chunk * 8 + rt) * ldb + k0 + cb;
            __builtin_amdgcn_global_load_lds(
                (const __attribute__((address_space(1))) void*)gb,
                (__attribute__((address_space(3))) void*)(ldsB3 + chunk * 1024), 16, 0, 0);
            const float4* sp = (const float4*)(S + (size_t)(brow + chunk * 8 + rt) * 2048 + k0 + cb);
            float4 a0 = sp[0], a1 = sp[1];
            float m = sm[p], iz = siz[p];
            float pv[8] = {a0.x, a0.y, a0.z, a0.w, a1.x, a1.y, a1.z, a1.w};
            unsigned ou[4];
            #pragma unroll
            for (int i = 0; i < 4; ++i) {
                float p0 = iz < 0.f ? -iz : __expf(pv[2 * i]     - m) * iz;
                float p1 = iz < 0.f ? -iz : __expf(pv[2 * i + 1] - m) * iz;
                ou[i] = (unsigned)f2bf(p0) | ((unsigned)f2bf(p1) << 16);
            }
            *(uint4*)&lA[chunk * 512 + l * 8] = make_uint4(ou[0], ou[1], ou[2], ou[3]);
        }
        __syncthreads();
        #pragma unroll
        for (int kk = 0; kk < 2; ++kk) {
            bf16x8 af[4], bfv[4];
            #pragma unroll
            for (int m = 0; m < 4; ++m)
                af[m] = *(const bf16x8*)&lA[(wr * 64 + m * 16 + (l & 15)) * 64 + kk * 32 + (l >> 4) * 8];
            #pragma unroll
            for (int n = 0; n < 4; ++n)
                bfv[n] = *(const bf16x8*)&lB[(wc * 64 + n * 16 + (l & 15)) * 64 + kk * 32 + (l >> 4) * 8];
            #pragma unroll
            for (int m = 0; m < 4; ++m)
                #pragma unroll
                for (int n = 0; n < 4; ++n)
                    acc[m][n] = __builtin_amdgcn_mfma_f32_16x16x32_bf16(af[m], bfv[n], acc[m][n], 0, 0, 0);
        }
    }

    const int lrow = (l >> 4) * 4, lcol = l & 15;
    #pragma unroll
    for (int m = 0; m < 4; ++m) {
        #pragma unroll
        for (int n = 0; n < 4; ++n) {
            int rr = brow + wr * 64 + m * 16 + lrow;
            int cc = bcol + wc * 64 + n * 16 + lcol;
            #pragma unroll
            for (int j = 0; j < 4; ++j)
                Cout[(size_t)blockIdx.z * sC + (size_t)(rr + j) * ldc + cc] = acc[m][n][j];
        }
    }
}

extern "C" void kernel_launch(void* const* d_in, const int* in_sizes, int n_in,
                              void* d_out, int out_size, void* d_ws, size_t ws_size,
                              hipStream_t stream) {
    const float* x  = (const float*)d_in[0];
    const float* Wq = (const float*)d_in[1];
    const float* Wk = (const float*)d_in[2];
    const float* Wv = (const float*)d_in[3];
    const unsigned int* mask = (const unsigned int*)d_in[4];
    float* out = (float*)d_out;

    char* p = (char*)d_ws;
    u16* Wt  = (u16*)p;  p += (size_t)3072 * 1024 * 2;
    u16* xb  = (u16*)p;  p += (size_t)8192 * 1024 * 2;
    u16* qkv = (u16*)p;  p += (size_t)8192 * 3072 * 2;
    u16* vt  = (u16*)p;  p += (size_t)4 * 1024 * 2048 * 2;
    char* base = p;
    const size_t sizeS  = (size_t)2048 * 2048 * 4;        // 16 MB per batch
    const size_t sizePt = (size_t)32 * 2048 * 8;          // 512 KB per batch
    const size_t sizeSt = (size_t)2048 * 8;               // 16 KB per batch
    bool batched = ws_size >= (size_t)(base - (char*)d_ws) + 4 * (sizeS + sizePt + sizeSt) + 8192;

    float* S; float2* part; float2* stats; unsigned char* nm;
    int nz = batched ? 4 : 1;
    S     = (float*)base;
    part  = (float2*)(base + nz * sizeS);
    stats = (float2*)(base + nz * (sizeS + sizePt));
    nm    = (unsigned char*)(base + nz * (sizeS + sizePt + sizeSt));

    normMask<<<1, 256, 0, stream>>>(mask, nm);
    transW<<<dim3(16, 16, 3), 256, 0, stream>>>(Wq, Wk, Wv, Wt);
    convX<<<2048, 256, 0, stream>>>(x, xb);
    // QKV: M=8192 N=3072 K=1024 -> 32x12 = 384 tiles (r4 config)
    gemm8p<0><<<dim3(384, 1, 1), 512, 0, stream>>>(
        xb, 1024, 0, Wt, 1024, 0, qkv, 3072, 0, 1024, 12, nullptr);
    transV<<<dim3(32, 16, 4), 256, 0, stream>>>(qkv, vt);

    if (batched) {
        gemm8p<1><<<dim3(64, 1, 4), 512, 0, stream>>>(
            qkv, 3072, (size_t)2048 * 3072, qkv + 1024, 3072, (size_t)2048 * 3072,
            S, 2048, (size_t)2048 * 2048, 1024, 8, part);
        combineStats<<<dim3(8, 4), 256, 0, stream>>>(part, stats, nm, 0);
        gemm_pv<<<dim3(16, 8, 4), 256, 0, stream>>>(
            S, (size_t)2048 * 2048, stats, vt, 2048, (size_t)1024 * 2048,
            out, 1024, (size_t)2048 * 1024, 2048);
    } else {
        for (int b = 0; b < 4; ++b) {
            const u16* Qb = qkv + (size_t)b * 2048 * 3072;
            gemm8p<1><<<dim3(64, 1, 1), 512, 0, stream>>>(
                Qb, 3072, 0, Qb + 1024, 3072, 0, S, 2048, 0, 1024, 8, part);
            combineStats<<<dim3(8, 1), 256, 0, stream>>>(part, stats, nm, b);
            gemm_pv<<<dim3(16, 8, 1), 256, 0, stream>>>(
                S, 0, stats, vt + (size_t)b * 1024 * 2048, 2048, 0,
                out + (size_t)b * 2048 * 1024, 1024, 0, 2048);
        }
    }
}